// Round 5
// baseline (2507.806 us; speedup 1.0000x reference)
//
#include <hip/hip_runtime.h>
#include <math.h>

// B=64, S=128, E=512, H=512, A=256, V=8192, T=32
#define BB 64
#define SS 128
#define EE 512
#define HH 512
#define AA 256
#define VV 8192
#define TT 32

typedef __bf16 bf16x8 __attribute__((ext_vector_type(8)));
typedef __bf16 bf16x4 __attribute__((ext_vector_type(4)));
typedef float  f32x4  __attribute__((ext_vector_type(4)));

__device__ __forceinline__ bf16x8 cvt_v(float4 u, float4 v) {
    bf16x8 r;
    r[0] = (__bf16)u.x; r[1] = (__bf16)u.y; r[2] = (__bf16)u.z; r[3] = (__bf16)u.w;
    r[4] = (__bf16)v.x; r[5] = (__bf16)v.y; r[6] = (__bf16)v.z; r[7] = (__bf16)v.w;
    return r;
}

__device__ __forceinline__ float tanh_fast(float x) {
    x = fminf(15.f, fmaxf(-15.f, x));
    float e = __expf(2.f * x);
    return (e - 1.f) / (e + 1.f);
}
__device__ __forceinline__ float sigmoid_fast(float x) {
    return 1.f / (1.f + __expf(-x));
}

#define LDW(d, p) { const float4* q_ = (const float4*)(p); d##0 = q_[0]; d##1 = q_[1]; d##2 = q_[2]; d##3 = q_[3]; }

// ---------------------------------------------------------------------------
// Device-wide barrier (cooperative launch guarantees co-residency).
// bar[0] = arrive counter, bar[1] = generation. Bounded spin: a broken
// barrier fails verification instead of hanging.
// ---------------------------------------------------------------------------
__device__ __forceinline__ void gbar(int* bar, int nblk) {
    __syncthreads();
    if (threadIdx.x == 0) {
        __threadfence();   // device-scope release of this block's writes
        int g = __hip_atomic_load(&bar[1], __ATOMIC_RELAXED, __HIP_MEMORY_SCOPE_AGENT);
        int a = __hip_atomic_fetch_add(&bar[0], 1, __ATOMIC_ACQ_REL, __HIP_MEMORY_SCOPE_AGENT);
        if (a == nblk - 1) {
            __hip_atomic_store(&bar[0], 0, __ATOMIC_RELAXED, __HIP_MEMORY_SCOPE_AGENT);
            __hip_atomic_fetch_add(&bar[1], 1, __ATOMIC_RELEASE, __HIP_MEMORY_SCOPE_AGENT);
        } else {
            int spins = 0;
            while (__hip_atomic_load(&bar[1], __ATOMIC_ACQUIRE, __HIP_MEMORY_SCOPE_AGENT) == g) {
                __builtin_amdgcn_s_sleep(2);
                if (++spins > (1 << 27)) break;   // fail-fast safety valve
            }
        }
        __threadfence();
    }
    __syncthreads();
}

// ---------------------------------------------------------------------------
// fp32 GEMM (NN): one-time enc_proj.
// ---------------------------------------------------------------------------
__global__ __launch_bounds__(256) void gemm_nn(
    const float* __restrict__ A, int lda,
    const float* __restrict__ B, int ldb,
    float* __restrict__ C, int ldc, int K)
{
    __shared__ float As[16][68];
    __shared__ float Bs[16][68];
    const int tid = threadIdx.x;
    const int m0 = blockIdx.x * 64, n0 = blockIdx.y * 64;
    const int row = tid >> 2, kq = (tid & 3) * 4;
    const int kk = tid >> 4, nq = (tid & 15) * 4;
    const int tm = tid >> 4, tn = tid & 15;
    float acc[4][4] = {};
    for (int k0 = 0; k0 < K; k0 += 16) {
        float4 av = *(const float4*)(A + (size_t)(m0 + row) * lda + k0 + kq);
        float4 bv = *(const float4*)(B + (size_t)(k0 + kk) * ldb + n0 + nq);
        As[kq + 0][row] = av.x; As[kq + 1][row] = av.y;
        As[kq + 2][row] = av.z; As[kq + 3][row] = av.w;
        *(float4*)&Bs[kk][nq] = bv;
        __syncthreads();
#pragma unroll
        for (int k = 0; k < 16; ++k) {
            float4 a = *(const float4*)&As[k][tm * 4];
            float4 b = *(const float4*)&Bs[k][tn * 4];
            acc[0][0] += a.x * b.x; acc[0][1] += a.x * b.y; acc[0][2] += a.x * b.z; acc[0][3] += a.x * b.w;
            acc[1][0] += a.y * b.x; acc[1][1] += a.y * b.y; acc[1][2] += a.y * b.z; acc[1][3] += a.y * b.w;
            acc[2][0] += a.z * b.x; acc[2][1] += a.z * b.y; acc[2][2] += a.z * b.z; acc[2][3] += a.z * b.w;
            acc[3][0] += a.w * b.x; acc[3][1] += a.w * b.y; acc[3][2] += a.w * b.z; acc[3][3] += a.w * b.w;
        }
        __syncthreads();
    }
#pragma unroll
    for (int i = 0; i < 4; ++i) {
        float4 r = make_float4(acc[i][0], acc[i][1], acc[i][2], acc[i][3]);
        *(float4*)(C + (size_t)(m0 + tm * 4 + i) * ldc + n0 + tn * 4) = r;
    }
}

// ---------------------------------------------------------------------------
// One-time fp32 -> bf16 conversions.
// ---------------------------------------------------------------------------
__global__ __launch_bounds__(256) void k_cvt_bf16(
    const float* __restrict__ src, __bf16* __restrict__ dst, size_t n4)
{
    size_t i = (size_t)blockIdx.x * 256 + threadIdx.x;
    if (i < n4) {
        float4 v = *(const float4*)(src + i * 4);
        bf16x4 r;
        r[0] = (__bf16)v.x; r[1] = (__bf16)v.y; r[2] = (__bf16)v.z; r[3] = (__bf16)v.w;
        *(bf16x4*)(dst + i * 4) = r;
    }
}

__global__ __launch_bounds__(256) void k_cvt_gates(
    const float* __restrict__ W_ih, const float* __restrict__ W_hh,
    __bf16* __restrict__ Wg)
{
    const int n = blockIdx.x;
    const int j = ((n & 3) << 9) + (n >> 2);
    for (int k = threadIdx.x * 4; k < 1536; k += 1024) {
        const float* src = (k < 512)  ? (W_hh + (size_t)j * 512 + k)
                         : (k < 1024) ? (W_ih + (size_t)j * 1024 + k)
                                      : (W_ih + (size_t)j * 1024 + (k - 1024));
        float4 v = *(const float4*)src;
        bf16x4 r;
        r[0] = (__bf16)v.x; r[1] = (__bf16)v.y; r[2] = (__bf16)v.z; r[3] = (__bf16)v.w;
        *(bf16x4*)(Wg + (size_t)n * 1536 + k) = r;
    }
}

// ===========================================================================
// PERSISTENT recurrence kernel: 64 blocks x 256 threads, cooperative launch,
// custom device barriers. Per step: attn phase (1 batch/block, proven 256-thr
// body) -> barrier -> gates phase (1 32-wide tile/block, proven body) -> barrier.
// Logits are NOT computed here (batched gemm_out_big afterwards).
// ===========================================================================
struct PB {
    const float* encf; const float* encp; const float* W_dec; const float* b_att;
    const float* v_att; const float* emb; const int* tgt;
    const __bf16* Wg; const float* b_ih; const float* b_hh;
    float* hbuf; float* cbuf;
    __bf16* xh; __bf16* hb0; __bf16* hb1; __bf16* XHN;
    int* bar;
};

__global__ __launch_bounds__(256) void persist2(PB p)
{
    __shared__ __align__(16) char smem[18432];
    const int blk = blockIdx.x;
    const int tid = threadIdx.x;
    const int wv = tid >> 6, lane = tid & 63;
    const int quad = lane >> 4, l16 = lane & 15;

    for (int t = 0; t < TT; ++t) {
        const __bf16* hold = (t & 1) ? p.hb1 : p.hb0;
        __bf16* hnew = (t & 1) ? p.hb0 : p.hb1;

        // ---------------- attention: batch b = blk ----------------
        {
            const int b = blk;
            float* sh   = (float*)smem;   // 512
            float* sdec = sh + 512;       // 256
            float* sv   = sdec + 256;     // 256
            float* sw   = sv + 256;       // 128
            sh[tid] = p.hbuf[(size_t)b * 512 + tid];
            sh[tid + 256] = p.hbuf[(size_t)b * 512 + 256 + tid];
            sv[tid] = p.v_att[tid];
            __syncthreads();
            // dec proj: a = tid, K=512
            {
                const float* w = p.W_dec + tid;
                float s = 0.f;
#pragma unroll 8
                for (int k = 0; k < 512; ++k) s += sh[k] * w[(size_t)k * 256];
                sdec[tid] = s + p.b_att[tid];
            }
            __syncthreads();
            // scores: 4 waves x 32 s each
            {
                const float* ep0 = p.encp + ((size_t)b * 128 + wv * 32) * 256;
                for (int i = 0; i < 32; ++i) {
                    const float* ep = ep0 + (size_t)i * 256;
                    float sum = 0.f;
#pragma unroll
                    for (int c = 0; c < 4; ++c) {
                        int a = lane + 64 * c;
                        sum += tanh_fast(ep[a] + sdec[a]) * sv[a];
                    }
#pragma unroll
                    for (int off = 32; off > 0; off >>= 1) sum += __shfl_down(sum, off);
                    if (lane == 0) sw[wv * 32 + i] = sum;
                }
            }
            __syncthreads();
            // softmax on wave 0
            if (tid < 64) {
                float a0 = sw[tid], a1 = sw[tid + 64];
                float m = fmaxf(a0, a1);
#pragma unroll
                for (int off = 32; off > 0; off >>= 1) m = fmaxf(m, __shfl_xor(m, off));
                float e0 = __expf(a0 - m), e1 = __expf(a1 - m);
                sw[tid] = e0; sw[tid + 64] = e1;
                float ss = e0 + e1;
#pragma unroll
                for (int off = 32; off > 0; off >>= 1) ss += __shfl_xor(ss, off);
                if (tid == 0) sh[0] = ss;
            }
            __syncthreads();
            const float inv = 1.f / sh[0];
            // ctx + XHN ctx half
            {
                const float* ef = p.encf + (size_t)b * (SS * EE) + tid;
                float cv0 = 0.f, cv1 = 0.f;
#pragma unroll 8
                for (int s = 0; s < 128; ++s) {
                    float w = sw[s];
                    cv0 += w * ef[(size_t)s * 512];
                    cv1 += w * ef[(size_t)s * 512 + 256];
                }
                const __bf16 c0 = (__bf16)(cv0 * inv);
                const __bf16 c1 = (__bf16)(cv1 * inv);
                p.xh[(size_t)b * 1024 + tid]       = c0;
                p.xh[(size_t)b * 1024 + 256 + tid] = c1;
                p.XHN[(size_t)(t * 64 + b) * 1024 + 512 + tid]       = c0;
                p.XHN[(size_t)(t * 64 + b) * 1024 + 768 + tid]       = c1;
            }
            // emb gather
            {
                const int tok = (t == 0) ? 0 : p.tgt[b * TT + t - 1];
                const float* em = p.emb + (size_t)tok * 512;
                p.xh[(size_t)b * 1024 + 512 + tid] = (__bf16)em[tid];
                p.xh[(size_t)b * 1024 + 768 + tid] = (__bf16)em[tid + 256];
            }
        }
        gbar(p.bar, 64);

        // ---------------- gates: tile n0 = blk*32 ----------------
        {
            __bf16 (*Ws)[32][72] = (__bf16 (*)[32][72])smem;        // 9216 B
            float  (*Cf)[36]     = (float (*)[36])(smem + 9216);    // 9216 B
            const int n0 = blk * 32;
            const int rowW = tid >> 3, kq8 = (tid & 7) * 8;
            const __bf16* rB = p.Wg + (size_t)(n0 + rowW) * 1536 + kq8;
            const __bf16* aHp = hold + (size_t)(wv * 16 + l16) * 512 + quad * 8;
            const __bf16* aXp = p.xh + (size_t)(wv * 16 + l16) * 1024 + quad * 8;

            f32x4 acc[2] = {{0,0,0,0},{0,0,0,0}};
            bf16x8 wcur = *(const bf16x8*)rB;
            bf16x8 wnxt = *(const bf16x8*)(rB + 64);
            bf16x8 aC0 = *(const bf16x8*)aHp, aC1 = *(const bf16x8*)(aHp + 32);
            bf16x8 aN0, aN1;
            for (int it = 0; it < 24; ++it) {
                *(bf16x8*)&Ws[it & 1][rowW][kq8] = wcur;
                __syncthreads();
                wcur = wnxt;
                if (it + 2 < 24) wnxt = *(const bf16x8*)(rB + (it + 2) * 64);
                if (it + 1 < 24) {
                    const int itn = it + 1;
                    const __bf16* ap = (itn < 8) ? (aHp + itn * 64) : (aXp + (itn - 8) * 64);
                    aN0 = *(const bf16x8*)ap; aN1 = *(const bf16x8*)(ap + 32);
                }
#pragma unroll
                for (int c = 0; c < 2; ++c) {
                    bf16x8 b0 = *(const bf16x8*)&Ws[it & 1][c * 16 + l16][quad * 8];
                    bf16x8 b1 = *(const bf16x8*)&Ws[it & 1][c * 16 + l16][quad * 8 + 32];
                    acc[c] = __builtin_amdgcn_mfma_f32_16x16x32_bf16(aC0, b0, acc[c], 0, 0, 0);
                    acc[c] = __builtin_amdgcn_mfma_f32_16x16x32_bf16(aC1, b1, acc[c], 0, 0, 0);
                }
                aC0 = aN0; aC1 = aN1;
            }
            __syncthreads();
#pragma unroll
            for (int r = 0; r < 4; ++r) {
                Cf[wv * 16 + quad * 4 + r][ 0 + l16] = acc[0][r];
                Cf[wv * 16 + quad * 4 + r][16 + l16] = acc[1][r];
            }
            __syncthreads();
            const int U0 = n0 >> 2;   // 8 units per block
#pragma unroll
            for (int pass = 0; pass < 2; ++pass) {
                const int it2 = tid + pass * 256;
                const int bb = it2 >> 3, ul = it2 & 7;
                const int u = U0 + ul;
                const float gi = Cf[bb][4 * ul + 0] + p.b_ih[u]          + p.b_hh[u];
                const float gf = Cf[bb][4 * ul + 1] + p.b_ih[512 + u]    + p.b_hh[512 + u];
                const float gg = Cf[bb][4 * ul + 2] + p.b_ih[1024 + u]   + p.b_hh[1024 + u];
                const float go = Cf[bb][4 * ul + 3] + p.b_ih[1536 + u]   + p.b_hh[1536 + u];
                const float si = sigmoid_fast(gi);
                const float sf = sigmoid_fast(gf);
                const float so = sigmoid_fast(go);
                const float cn = sf * p.cbuf[bb * 512 + u] + si * tanh_fast(gg);
                const float hn = so * tanh_fast(cn);
                p.cbuf[bb * 512 + u] = cn;
                p.hbuf[bb * 512 + u] = hn;
                const __bf16 hb = (__bf16)hn;
                hnew[(size_t)bb * 512 + u] = hb;
                p.XHN[(size_t)(t * 64 + bb) * 1024 + u] = hb;
            }
        }
        gbar(p.bar, 64);
    }
}

// ---------------------------------------------------------------------------
// Fallback attn (round-4 proven, 64 x 1024thr).
// ---------------------------------------------------------------------------
__global__ __launch_bounds__(1024) void attn_step(
    const float* __restrict__ encf, const float* __restrict__ encp,
    const float* __restrict__ W_dec, const float* __restrict__ b_att,
    const float* __restrict__ v_att, const float* __restrict__ emb,
    const int*   __restrict__ tgt, const float* __restrict__ h,
    __bf16* __restrict__ xh_cur, __bf16* __restrict__ XHN, int t)
{
    const int b = blockIdx.x;
    const int tid = threadIdx.x;
    __shared__ float sh[512];
    __shared__ float sdec[256];
    __shared__ float sv[256];
    __shared__ float sw[128], st[128];
    __shared__ float part[4][256];
    __shared__ float cpart[2][512];

    if (tid < 512) sh[tid] = h[(size_t)b * 512 + tid];
    else if (tid < 768) sv[tid - 512] = v_att[tid - 512];
    __syncthreads();
    {
        const int a = tid & 255, kq = tid >> 8;
        const float* w = W_dec + (size_t)kq * 128 * 256 + a;
        const float* hp = sh + kq * 128;
        float s = 0.f;
#pragma unroll 8
        for (int k = 0; k < 128; ++k) s += hp[k] * w[(size_t)k * 256];
        part[kq][a] = s;
    }
    __syncthreads();
    if (tid < 256)
        sdec[tid] = part[0][tid] + part[1][tid] + part[2][tid] + part[3][tid] + b_att[tid];
    __syncthreads();
    {
        const int wv = tid >> 6, lane = tid & 63;
#pragma unroll
        for (int i = 0; i < 8; ++i) {
            const int s = wv * 8 + i;
            const float* ep = encp + ((size_t)b * 128 + s) * 256;
            float sum = 0.f;
#pragma unroll
            for (int c = 0; c < 4; ++c) {
                int a = lane + 64 * c;
                sum += tanh_fast(ep[a] + sdec[a]) * sv[a];
            }
#pragma unroll
            for (int off = 32; off > 0; off >>= 1) sum += __shfl_down(sum, off);
            if (lane == 0) sw[s] = sum;
        }
    }
    __syncthreads();
    if (tid < 128) st[tid] = sw[tid];
    __syncthreads();
    for (int off = 64; off > 0; off >>= 1) {
        if (tid < off) st[tid] = fmaxf(st[tid], st[tid + off]);
        __syncthreads();
    }
    const float mx = st[0];
    __syncthreads();
    if (tid < 128) { float ex = __expf(sw[tid] - mx); sw[tid] = ex; st[tid] = ex; }
    __syncthreads();
    for (int off = 64; off > 0; off >>= 1) {
        if (tid < off) st[tid] += st[tid + off];
        __syncthreads();
    }
    {
        const int e = tid & 511, half = tid >> 9;
        const float* ef = encf + (size_t)b * (SS * EE) + (size_t)half * 64 * 512 + e;
        const float* wp = sw + half * 64;
        float cv = 0.f;
#pragma unroll 8
        for (int s = 0; s < 64; ++s) cv += wp[s] * ef[(size_t)s * 512];
        cpart[half][e] = cv;
    }
    __syncthreads();
    const float inv = 1.f / st[0];
    if (tid < 512) {
        const __bf16 cv = (__bf16)((cpart[0][tid] + cpart[1][tid]) * inv);
        xh_cur[(size_t)b * 1024 + tid] = cv;
        XHN[(size_t)(t * 64 + b) * 1024 + 512 + tid] = cv;
    } else {
        const int e = tid - 512;
        const int tok = (t == 0) ? 0 : tgt[b * TT + t - 1];
        xh_cur[(size_t)b * 1024 + 512 + e] = (__bf16)emb[(size_t)tok * 512 + e];
    }
}

// ---------------------------------------------------------------------------
// Fallback gates (round-4 proven), 64 x 256thr.
// ---------------------------------------------------------------------------
template<bool BF16W>
__global__ __launch_bounds__(256) void gemm_gates_lstm(
    const __bf16* __restrict__ h_old, const __bf16* __restrict__ xh_ce,
    const float* __restrict__ W_ih, const float* __restrict__ W_hh,
    const __bf16* __restrict__ Wg,
    const float* __restrict__ b_ih, const float* __restrict__ b_hh,
    float* __restrict__ hbuf, float* __restrict__ cbuf,
    __bf16* __restrict__ h_new, __bf16* __restrict__ XHN, int t)
{
    __shared__ __align__(16) char smem[18432];
    __bf16 (*Ws)[32][72] = (__bf16 (*)[32][72])smem;
    float  (*Cf)[36]     = (float (*)[36])(smem + 9216);
    const int tid = threadIdx.x;
    const int wv = tid >> 6, lane = tid & 63;
    const int quad = lane >> 4, l16 = lane & 15;
    const int n0 = blockIdx.x * 32;
    const int rowW = tid >> 3, kq8 = (tid & 7) * 8;

    const __bf16* rB = nullptr;
    const float *rH = nullptr, *rI = nullptr;
    if constexpr (BF16W) {
        rB = Wg + (size_t)(n0 + rowW) * 1536 + kq8;
    } else {
        const int nglob = n0 + rowW;
        const int j = ((nglob & 3) << 9) + (nglob >> 2);
        rH = W_hh + (size_t)j * 512;
        rI = W_ih + (size_t)j * 1024;
    }
    auto wld = [&](int it) -> bf16x8 {
        if constexpr (BF16W) {
            return *(const bf16x8*)(rB + it * 64);
        } else {
            const int k = it * 64 + kq8;
            const float* s = (k < 512) ? (rH + k)
                           : (k < 1024 ? rI + k : rI + (k - 1024));
            const float4* q = (const float4*)s;
            return cvt_v(q[0], q[1]);
        }
    };
    const __bf16* aHp = h_old + (size_t)(wv * 16 + l16) * 512 + quad * 8;
    const __bf16* aXp = xh_ce + (size_t)(wv * 16 + l16) * 1024 + quad * 8;

    f32x4 acc[2] = {{0,0,0,0},{0,0,0,0}};
    bf16x8 wcur = wld(0), wnxt = wld(1);
    bf16x8 aC0 = *(const bf16x8*)aHp, aC1 = *(const bf16x8*)(aHp + 32);
    bf16x8 aN0, aN1;
    for (int it = 0; it < 24; ++it) {
        *(bf16x8*)&Ws[it & 1][rowW][kq8] = wcur;
        __syncthreads();
        wcur = wnxt;
        if (it + 2 < 24) wnxt = wld(it + 2);
        if (it + 1 < 24) {
            const int itn = it + 1;
            const __bf16* ap = (itn < 8) ? (aHp + itn * 64) : (aXp + (itn - 8) * 64);
            aN0 = *(const bf16x8*)ap; aN1 = *(const bf16x8*)(ap + 32);
        }
#pragma unroll
        for (int c = 0; c < 2; ++c) {
            bf16x8 b0 = *(const bf16x8*)&Ws[it & 1][c * 16 + l16][quad * 8];
            bf16x8 b1 = *(const bf16x8*)&Ws[it & 1][c * 16 + l16][quad * 8 + 32];
            acc[c] = __builtin_amdgcn_mfma_f32_16x16x32_bf16(aC0, b0, acc[c], 0, 0, 0);
            acc[c] = __builtin_amdgcn_mfma_f32_16x16x32_bf16(aC1, b1, acc[c], 0, 0, 0);
        }
        aC0 = aN0; aC1 = aN1;
    }
    __syncthreads();
#pragma unroll
    for (int r = 0; r < 4; ++r) {
        Cf[wv * 16 + quad * 4 + r][ 0 + l16] = acc[0][r];
        Cf[wv * 16 + quad * 4 + r][16 + l16] = acc[1][r];
    }
    __syncthreads();
    const int U0 = n0 >> 2;
#pragma unroll
    for (int pass = 0; pass < 2; ++pass) {
        const int it2 = tid + pass * 256;
        const int bb = it2 >> 3, ul = it2 & 7;
        const int u = U0 + ul;
        const float gi = Cf[bb][4 * ul + 0] + b_ih[u]          + b_hh[u];
        const float gf = Cf[bb][4 * ul + 1] + b_ih[512 + u]    + b_hh[512 + u];
        const float gg = Cf[bb][4 * ul + 2] + b_ih[1024 + u]   + b_hh[1024 + u];
        const float go = Cf[bb][4 * ul + 3] + b_ih[1536 + u]   + b_hh[1536 + u];
        const float si = sigmoid_fast(gi);
        const float sf = sigmoid_fast(gf);
        const float so = sigmoid_fast(go);
        const float cn = sf * cbuf[bb * 512 + u] + si * tanh_fast(gg);
        const float hn = so * tanh_fast(cn);
        cbuf[bb * 512 + u] = cn;
        hbuf[bb * 512 + u] = hn;
        const __bf16 hb = (__bf16)hn;
        h_new[(size_t)bb * 512 + u] = hb;
        if (XHN) XHN[(size_t)(t * 64 + bb) * 1024 + u] = hb;
    }
}

// ---------------------------------------------------------------------------
// Batched logits GEMM with XCD swizzle: blocks sharing an N-column of W_out
// land on the same XCD (per-XCD Wo slice = 2 MB -> L2-resident).
// ---------------------------------------------------------------------------
template<bool BF16W>
__global__ __launch_bounds__(256) void gemm_out_big(
    const __bf16* __restrict__ XHN,
    const float*  __restrict__ Wo_f,
    const __bf16* __restrict__ Wo_b,
    const float*  __restrict__ b_out,
    float* __restrict__ out)
{
    __shared__ __bf16 Bs[2][64][76];   // padded 72->76: breaks bank aliasing
    const int tid = threadIdx.x;
    const int blks = ((blockIdx.x & 7) << 8) | ((int)blockIdx.x >> 3);  // XCD swizzle
    const int mt = blks & 15;
    const int n0 = (blks >> 4) * 64;
    const int wv = tid >> 6, lane = tid & 63;
    const int quad = lane >> 4, l16 = lane & 15;
    const int row = tid >> 2, cq = tid & 3;

    const __bf16* aP0 = XHN + (size_t)(mt * 128 + wv * 16 + l16) * 1024 + quad * 8;
    const __bf16* aP1 = aP0 + (size_t)64 * 1024;

    f32x4 acc[8] = {{0,0,0,0},{0,0,0,0},{0,0,0,0},{0,0,0,0},
                    {0,0,0,0},{0,0,0,0},{0,0,0,0},{0,0,0,0}};
    float4 wA0, wA1, wA2, wA3, wB0, wB1, wB2, wB3;
    bf16x8 pA0, pA1, pB0, pB1;
    const float*  bsf = nullptr;
    const __bf16* bsb = nullptr;
    if constexpr (BF16W) {
        bsb = Wo_b + (size_t)(n0 + row) * 1024 + cq * 16;
        const bf16x8* q0 = (const bf16x8*)bsb;        pA0 = q0[0]; pA1 = q0[1];
        const bf16x8* q1 = (const bf16x8*)(bsb + 64); pB0 = q1[0]; pB1 = q1[1];
    } else {
        bsf = Wo_f + (size_t)(n0 + row) * 1024 + cq * 16;
        LDW(wA, bsf); LDW(wB, bsf + 64);
    }
    bf16x8 a0C0 = *(const bf16x8*)aP0, a0C1 = *(const bf16x8*)(aP0 + 32);
    bf16x8 a1C0 = *(const bf16x8*)aP1, a1C1 = *(const bf16x8*)(aP1 + 32);
    bf16x8 a0N0, a0N1, a1N0, a1N1;

    for (int it = 0; it < 16; ++it) {
        __bf16* dst = &Bs[it & 1][row][cq * 16];
        if constexpr (BF16W) {
            *(bf16x8*)dst       = pA0;
            *(bf16x8*)(dst + 8) = pA1;
        } else {
            *(bf16x8*)dst       = cvt_v(wA0, wA1);
            *(bf16x8*)(dst + 8) = cvt_v(wA2, wA3);
        }
        __syncthreads();
        if constexpr (BF16W) {
            pA0 = pB0; pA1 = pB1;
            if (it + 2 < 16) {
                const bf16x8* q = (const bf16x8*)(bsb + (it + 2) * 64);
                pB0 = q[0]; pB1 = q[1];
            }
        } else {
            wA0 = wB0; wA1 = wB1; wA2 = wB2; wA3 = wB3;
            if (it + 2 < 16) LDW(wB, bsf + (it + 2) * 64);
        }
        if (it + 1 < 16) {
            const __bf16* ap0 = aP0 + (it + 1) * 64;
            const __bf16* ap1 = aP1 + (it + 1) * 64;
            a0N0 = *(const bf16x8*)ap0; a0N1 = *(const bf16x8*)(ap0 + 32);
            a1N0 = *(const bf16x8*)ap1; a1N1 = *(const bf16x8*)(ap1 + 32);
        }
#pragma unroll
        for (int c = 0; c < 4; ++c) {
            bf16x8 b0 = *(const bf16x8*)&Bs[it & 1][c * 16 + l16][quad * 8];
            bf16x8 b1 = *(const bf16x8*)&Bs[it & 1][c * 16 + l16][quad * 8 + 32];
            acc[c]     = __builtin_amdgcn_mfma_f32_16x16x32_bf16(a0C0, b0, acc[c],     0, 0, 0);
            acc[c]     = __builtin_amdgcn_mfma_f32_16x16x32_bf16(a0C1, b1, acc[c],     0, 0, 0);
            acc[4 + c] = __builtin_amdgcn_mfma_f32_16x16x32_bf16(a1C0, b0, acc[4 + c], 0, 0, 0);
            acc[4 + c] = __builtin_amdgcn_mfma_f32_16x16x32_bf16(a1C1, b1, acc[4 + c], 0, 0, 0);
        }
        a0C0 = a0N0; a0C1 = a0N1; a1C0 = a1N0; a1C1 = a1N1;
    }
    const int nb = n0 + l16;
#pragma unroll
    for (int h2 = 0; h2 < 2; ++h2) {
#pragma unroll
        for (int r = 0; r < 4; ++r) {
            const int rglob = mt * 128 + h2 * 64 + wv * 16 + quad * 4 + r;
            const int tstep = rglob >> 6, bb = rglob & 63;
            float* orow = out + (size_t)bb * (TT * VV) + (size_t)tstep * VV + nb;
            orow[ 0] = acc[h2 * 4 + 0][r] + b_out[nb +  0];
            orow[16] = acc[h2 * 4 + 1][r] + b_out[nb + 16];
            orow[32] = acc[h2 * 4 + 2][r] + b_out[nb + 32];
            orow[48] = acc[h2 * 4 + 3][r] + b_out[nb + 48];
        }
    }
}

// ---------------------------------------------------------------------------
__global__ void k_zero_f(float* p, int n) {
    int i = blockIdx.x * 256 + threadIdx.x;
    if (i < n) p[i] = 0.f;
}
__global__ void k_zero_bf(__bf16* p, int n) {
    int i = blockIdx.x * 256 + threadIdx.x;
    if (i < n) p[i] = (__bf16)0.f;
}

// ---------------------------------------------------------------------------
extern "C" void kernel_launch(void* const* d_in, const int* in_sizes, int n_in,
                              void* d_out, int out_size, void* d_ws, size_t ws_size,
                              hipStream_t stream)
{
    (void)in_sizes; (void)n_in; (void)out_size;
    const float* encf  = (const float*)d_in[0];
    const int*   tgt   = (const int*)  d_in[1];
    const float* emb   = (const float*)d_in[2];
    const float* W_enc = (const float*)d_in[3];
    const float* W_dec = (const float*)d_in[4];
    const float* b_att = (const float*)d_in[5];
    const float* v_att = (const float*)d_in[6];
    const float* W_ih  = (const float*)d_in[7];
    const float* W_hh  = (const float*)d_in[8];
    const float* b_ih  = (const float*)d_in[9];
    const float* b_hh  = (const float*)d_in[10];
    const float* W_out = (const float*)d_in[11];
    const float* b_out = (const float*)d_in[12];
    float* out = (float*)d_out;

    float* ws = (float*)d_ws;
    size_t off = 0;
    auto alloc = [&](size_t n) { float* p = ws + off; off += (n + 255) & ~(size_t)255; return p; };
    float*  encp = alloc((size_t)BB * SS * AA);
    float*  hbuf = alloc((size_t)BB * HH);   // hbuf, cbuf, bar contiguous: one zero pass
    float*  cbuf = alloc((size_t)BB * HH);
    int*    bar  = (int*)alloc(256);
    __bf16* xh0  = (__bf16*)alloc((size_t)BB * 1024 / 2);
    __bf16* xh1  = (__bf16*)alloc((size_t)BB * 1024 / 2);
    __bf16* hb0  = (__bf16*)alloc((size_t)BB * HH / 2);
    __bf16* hb1  = (__bf16*)alloc((size_t)BB * HH / 2);
    __bf16* XHN  = (__bf16*)alloc((size_t)2048 * 1024 / 2);
    __bf16* Wg   = (__bf16*)alloc((size_t)2048 * 1536 / 2);
    const size_t off1 = off;
    __bf16* Wo_b = (__bf16*)alloc((size_t)VV * 1024 / 2);
    const size_t off2 = off;

    const int level = (off2 * sizeof(float) <= ws_size) ? 2
                    : (off1 * sizeof(float) <= ws_size) ? 1 : 0;

    k_zero_f<<<(2 * BB * HH + 256 + 255) / 256, 256, 0, stream>>>(hbuf, 2 * BB * HH + 256);
    k_zero_bf<<<(BB * HH + 255) / 256, 256, 0, stream>>>(hb0, BB * HH);
    gemm_nn<<<dim3(BB * SS / 64, AA / 64), 256, 0, stream>>>(encf, EE, W_enc, AA, encp, AA, EE);

    if (level >= 1) {
        k_cvt_gates<<<2048, 256, 0, stream>>>(W_ih, W_hh, Wg);
        if (level == 2)
            k_cvt_bf16<<<(int)(((size_t)VV * 1024 / 4 + 255) / 256), 256, 0, stream>>>(
                W_out, Wo_b, (size_t)VV * 1024 / 4);

        PB pb;
        pb.encf = encf; pb.encp = encp; pb.W_dec = W_dec; pb.b_att = b_att;
        pb.v_att = v_att; pb.emb = emb; pb.tgt = tgt;
        pb.Wg = Wg; pb.b_ih = b_ih; pb.b_hh = b_hh;
        pb.hbuf = hbuf; pb.cbuf = cbuf;
        pb.xh = xh0; pb.hb0 = hb0; pb.hb1 = hb1; pb.XHN = XHN;
        pb.bar = bar;
        void* kargs[] = { &pb };
        void (*fp)(PB) = persist2;
        hipError_t rc = hipLaunchCooperativeKernel((const void*)fp, dim3(64), dim3(256),
                                                   kargs, 0, stream);
        if (rc != hipSuccess) {
            // Fallback: proven round-4 separate-launch loop.
            for (int t = 0; t < TT; ++t) {
                __bf16* hold = (t & 1) ? hb1 : hb0;
                __bf16* hnew = (t & 1) ? hb0 : hb1;
                attn_step<<<64, 1024, 0, stream>>>(
                    encf, encp, W_dec, b_att, v_att, emb, tgt, hbuf, xh0, XHN, t);
                gemm_gates_lstm<true><<<64, 256, 0, stream>>>(
                    hold, xh0, W_ih, W_hh, Wg, b_ih, b_hh, hbuf, cbuf, hnew, XHN, t);
            }
        }
        if (level == 2)
            gemm_out_big<true><<<2048, 256, 0, stream>>>(XHN, W_out, Wo_b, b_out, out);
        else
            gemm_out_big<false><<<2048, 256, 0, stream>>>(XHN, W_out, Wo_b, b_out, out);
    } else {
        // Minimal-workspace fallback: fp32 weights, separate launches.
        for (int t = 0; t < TT; ++t) {
            __bf16* hold = (t & 1) ? hb1 : hb0;
            __bf16* hnew = (t & 1) ? hb0 : hb1;
            attn_step<<<64, 1024, 0, stream>>>(
                encf, encp, W_dec, b_att, v_att, emb, tgt, hbuf, xh0, XHN, t);
            gemm_gates_lstm<false><<<64, 256, 0, stream>>>(
                hold, xh0, W_ih, W_hh, nullptr, b_ih, b_hh, hbuf, cbuf, hnew, XHN, t);
        }
        gemm_out_big<false><<<2048, 256, 0, stream>>>(XHN, W_out, nullptr, b_out, out);
    }
}

// Round 7
// 1959.844 us; speedup vs baseline: 1.2796x; 1.2796x over previous
//
#include <hip/hip_runtime.h>
#include <math.h>

// B=64, S=128, E=512, H=512, A=256, V=8192, T=32
#define BB 64
#define SS 128
#define EE 512
#define HH 512
#define AA 256
#define VV 8192
#define TT 32

typedef __bf16 bf16x8 __attribute__((ext_vector_type(8)));
typedef __bf16 bf16x4 __attribute__((ext_vector_type(4)));
typedef float  f32x4  __attribute__((ext_vector_type(4)));

__device__ __forceinline__ bf16x8 cvt_v(float4 u, float4 v) {
    bf16x8 r;
    r[0] = (__bf16)u.x; r[1] = (__bf16)u.y; r[2] = (__bf16)u.z; r[3] = (__bf16)u.w;
    r[4] = (__bf16)v.x; r[5] = (__bf16)v.y; r[6] = (__bf16)v.z; r[7] = (__bf16)v.w;
    return r;
}

__device__ __forceinline__ float tanh_fast(float x) {
    x = fminf(15.f, fmaxf(-15.f, x));
    float e = __expf(2.f * x);
    return (e - 1.f) / (e + 1.f);
}
__device__ __forceinline__ float sigmoid_fast(float x) {
    return 1.f / (1.f + __expf(-x));
}

#define LDW(d, p) { const float4* q_ = (const float4*)(p); d##0 = q_[0]; d##1 = q_[1]; d##2 = q_[2]; d##3 = q_[3]; }

// ---------------------------------------------------------------------------
// fp32 GEMM (NN): fallback enc_proj (levels < 3).
// ---------------------------------------------------------------------------
__global__ __launch_bounds__(256) void gemm_nn(
    const float* __restrict__ A, int lda,
    const float* __restrict__ B, int ldb,
    float* __restrict__ C, int ldc, int K)
{
    __shared__ float As[16][68];
    __shared__ float Bs[16][68];
    const int tid = threadIdx.x;
    const int m0 = blockIdx.x * 64, n0 = blockIdx.y * 64;
    const int row = tid >> 2, kq = (tid & 3) * 4;
    const int kk = tid >> 4, nq = (tid & 15) * 4;
    const int tm = tid >> 4, tn = tid & 15;
    float acc[4][4] = {};
    for (int k0 = 0; k0 < K; k0 += 16) {
        float4 av = *(const float4*)(A + (size_t)(m0 + row) * lda + k0 + kq);
        float4 bv = *(const float4*)(B + (size_t)(k0 + kk) * ldb + n0 + nq);
        As[kq + 0][row] = av.x; As[kq + 1][row] = av.y;
        As[kq + 2][row] = av.z; As[kq + 3][row] = av.w;
        *(float4*)&Bs[kk][nq] = bv;
        __syncthreads();
#pragma unroll
        for (int k = 0; k < 16; ++k) {
            float4 a = *(const float4*)&As[k][tm * 4];
            float4 b = *(const float4*)&Bs[k][tn * 4];
            acc[0][0] += a.x * b.x; acc[0][1] += a.x * b.y; acc[0][2] += a.x * b.z; acc[0][3] += a.x * b.w;
            acc[1][0] += a.y * b.x; acc[1][1] += a.y * b.y; acc[1][2] += a.y * b.z; acc[1][3] += a.y * b.w;
            acc[2][0] += a.z * b.x; acc[2][1] += a.z * b.y; acc[2][2] += a.z * b.z; acc[2][3] += a.z * b.w;
            acc[3][0] += a.w * b.x; acc[3][1] += a.w * b.y; acc[3][2] += a.w * b.z; acc[3][3] += a.w * b.w;
        }
        __syncthreads();
    }
#pragma unroll
    for (int i = 0; i < 4; ++i) {
        float4 r = make_float4(acc[i][0], acc[i][1], acc[i][2], acc[i][3]);
        *(float4*)(C + (size_t)(m0 + tm * 4 + i) * ldc + n0 + tn * 4) = r;
    }
}

// ---------------------------------------------------------------------------
// One-time conversions.
// ---------------------------------------------------------------------------
__global__ __launch_bounds__(256) void k_cvt_bf16(
    const float* __restrict__ src, __bf16* __restrict__ dst, size_t n4)
{
    size_t i = (size_t)blockIdx.x * 256 + threadIdx.x;
    if (i < n4) {
        float4 v = *(const float4*)(src + i * 4);
        bf16x4 r;
        r[0] = (__bf16)v.x; r[1] = (__bf16)v.y; r[2] = (__bf16)v.z; r[3] = (__bf16)v.w;
        *(bf16x4*)(dst + i * 4) = r;
    }
}

__global__ __launch_bounds__(256) void k_cvt_gates(
    const float* __restrict__ W_ih, const float* __restrict__ W_hh,
    __bf16* __restrict__ Wg)
{
    const int n = blockIdx.x;
    const int j = ((n & 3) << 9) + (n >> 2);
    for (int k = threadIdx.x * 4; k < 1536; k += 1024) {
        const float* src = (k < 512)  ? (W_hh + (size_t)j * 512 + k)
                         : (k < 1024) ? (W_ih + (size_t)j * 1024 + k)
                                      : (W_ih + (size_t)j * 1024 + (k - 1024));
        float4 v = *(const float4*)src;
        bf16x4 r;
        r[0] = (__bf16)v.x; r[1] = (__bf16)v.y; r[2] = (__bf16)v.z; r[3] = (__bf16)v.w;
        *(bf16x4*)(Wg + (size_t)n * 1536 + k) = r;
    }
}

// W_encT[a][k] = W_enc[k][a], bf16.
__global__ __launch_bounds__(256) void k_cvt_wencT(
    const float* __restrict__ W_enc, __bf16* __restrict__ WT)
{
    const int a = blockIdx.x;
    for (int k = threadIdx.x; k < 512; k += 256)
        WT[(size_t)a * 512 + k] = (__bf16)W_enc[(size_t)k * 256 + a];
}

// ---------------------------------------------------------------------------
// MFMA enc_proj: encp[8192][256] = encf_bf[8192][512] @ W_encT[256][512]^T.
// Grid 256: mt = blk>>2 (M-tile 128), nt = blk&3 (N-tile 64). K=512 (8 iters).
// ---------------------------------------------------------------------------
__global__ __launch_bounds__(256) void gemm_encp(
    const __bf16* __restrict__ A,    // [8192][512]
    const __bf16* __restrict__ Bw,   // [256][512]
    float* __restrict__ C)           // [8192][256]
{
    __shared__ __bf16 Bs[2][64][76];
    const int tid = threadIdx.x;
    const int mt = (int)blockIdx.x >> 2;
    const int n0 = ((int)blockIdx.x & 3) * 64;
    const int wv = tid >> 6, lane = tid & 63;
    const int quad = lane >> 4, l16 = lane & 15;
    const int row = tid >> 2, cq = tid & 3;

    const __bf16* aP0 = A + (size_t)(mt * 128 + wv * 16 + l16) * 512 + quad * 8;
    const __bf16* aP1 = aP0 + (size_t)64 * 512;

    f32x4 acc[8] = {{0,0,0,0},{0,0,0,0},{0,0,0,0},{0,0,0,0},
                    {0,0,0,0},{0,0,0,0},{0,0,0,0},{0,0,0,0}};
    const __bf16* bsb = Bw + (size_t)(n0 + row) * 512 + cq * 16;
    bf16x8 pA0 = ((const bf16x8*)bsb)[0], pA1 = ((const bf16x8*)bsb)[1];
    bf16x8 pB0 = ((const bf16x8*)(bsb + 64))[0], pB1 = ((const bf16x8*)(bsb + 64))[1];
    bf16x8 a0C0 = *(const bf16x8*)aP0, a0C1 = *(const bf16x8*)(aP0 + 32);
    bf16x8 a1C0 = *(const bf16x8*)aP1, a1C1 = *(const bf16x8*)(aP1 + 32);
    bf16x8 a0N0, a0N1, a1N0, a1N1;

    for (int it = 0; it < 8; ++it) {
        __bf16* dst = &Bs[it & 1][row][cq * 16];
        *(bf16x8*)dst       = pA0;
        *(bf16x8*)(dst + 8) = pA1;
        __syncthreads();
        pA0 = pB0; pA1 = pB1;
        if (it + 2 < 8) {
            const bf16x8* q = (const bf16x8*)(bsb + (it + 2) * 64);
            pB0 = q[0]; pB1 = q[1];
        }
        if (it + 1 < 8) {
            const __bf16* ap0 = aP0 + (it + 1) * 64;
            const __bf16* ap1 = aP1 + (it + 1) * 64;
            a0N0 = *(const bf16x8*)ap0; a0N1 = *(const bf16x8*)(ap0 + 32);
            a1N0 = *(const bf16x8*)ap1; a1N1 = *(const bf16x8*)(ap1 + 32);
        }
#pragma unroll
        for (int c = 0; c < 4; ++c) {
            bf16x8 b0 = *(const bf16x8*)&Bs[it & 1][c * 16 + l16][quad * 8];
            bf16x8 b1 = *(const bf16x8*)&Bs[it & 1][c * 16 + l16][quad * 8 + 32];
            acc[c]     = __builtin_amdgcn_mfma_f32_16x16x32_bf16(a0C0, b0, acc[c],     0, 0, 0);
            acc[c]     = __builtin_amdgcn_mfma_f32_16x16x32_bf16(a0C1, b1, acc[c],     0, 0, 0);
            acc[4 + c] = __builtin_amdgcn_mfma_f32_16x16x32_bf16(a1C0, b0, acc[4 + c], 0, 0, 0);
            acc[4 + c] = __builtin_amdgcn_mfma_f32_16x16x32_bf16(a1C1, b1, acc[4 + c], 0, 0, 0);
        }
        a0C0 = a0N0; a0C1 = a0N1; a1C0 = a1N0; a1C1 = a1N1;
    }
    const int nb = n0 + l16;
#pragma unroll
    for (int h2 = 0; h2 < 2; ++h2) {
#pragma unroll
        for (int r = 0; r < 4; ++r) {
            const int rglob = mt * 128 + h2 * 64 + wv * 16 + quad * 4 + r;
            float* orow = C + (size_t)rglob * 256 + nb;
            orow[ 0] = acc[h2 * 4 + 0][r];
            orow[16] = acc[h2 * 4 + 1][r];
            orow[32] = acc[h2 * 4 + 2][r];
            orow[48] = acc[h2 * 4 + 3][r];
        }
    }
}

// ---------------------------------------------------------------------------
// WIDE attention step: 256 blocks x 256 thr.  b = blk>>2, q = blk&3.
// dec-proj/scores/softmax computed redundantly per quarter (verbatim the
// round-3-verified 256-thr body); ctx + emb split 4x along E (128 cols each).
// ---------------------------------------------------------------------------
__global__ __launch_bounds__(256) void attn_step_w(
    const float* __restrict__ encf, const float* __restrict__ encp,
    const float* __restrict__ W_dec, const float* __restrict__ b_att,
    const float* __restrict__ v_att, const float* __restrict__ emb,
    const int*   __restrict__ tgt, const float* __restrict__ h,
    __bf16* __restrict__ xh_cur, __bf16* __restrict__ XHN, int t)
{
    const int b = (int)blockIdx.x >> 2, q = (int)blockIdx.x & 3;
    const int tid = threadIdx.x;
    const int wv = tid >> 6, lane = tid & 63;
    __shared__ float sh[512];
    __shared__ float sdec[256];
    __shared__ float sv[256];
    __shared__ float sw[128];
    __shared__ float cpart[2][128];

    sh[tid] = h[(size_t)b * 512 + tid];
    sh[tid + 256] = h[(size_t)b * 512 + 256 + tid];
    sv[tid] = v_att[tid];
    __syncthreads();
    // dec proj: a = tid, K=512
    {
        const float* w = W_dec + tid;
        float s = 0.f;
#pragma unroll 8
        for (int k = 0; k < 512; ++k) s += sh[k] * w[(size_t)k * 256];
        sdec[tid] = s + b_att[tid];
    }
    __syncthreads();
    // scores: 4 waves x 32 s each
    {
        const float* ep0 = encp + ((size_t)b * 128 + wv * 32) * 256;
        for (int i = 0; i < 32; ++i) {
            const float* ep = ep0 + (size_t)i * 256;
            float sum = 0.f;
#pragma unroll
            for (int c = 0; c < 4; ++c) {
                int a = lane + 64 * c;
                sum += tanh_fast(ep[a] + sdec[a]) * sv[a];
            }
#pragma unroll
            for (int off = 32; off > 0; off >>= 1) sum += __shfl_down(sum, off);
            if (lane == 0) sw[wv * 32 + i] = sum;
        }
    }
    __syncthreads();
    // softmax on wave 0
    if (tid < 64) {
        float a0 = sw[tid], a1 = sw[tid + 64];
        float m = fmaxf(a0, a1);
#pragma unroll
        for (int off = 32; off > 0; off >>= 1) m = fmaxf(m, __shfl_xor(m, off));
        float e0 = __expf(a0 - m), e1 = __expf(a1 - m);
        sw[tid] = e0; sw[tid + 64] = e1;
        float ss = e0 + e1;
#pragma unroll
        for (int off = 32; off > 0; off >>= 1) ss += __shfl_xor(ss, off);
        if (tid == 0) sh[0] = ss;
    }
    __syncthreads();
    const float inv = 1.f / sh[0];
    // ctx slice: e in [q*128, q*128+128); split s in halves across tid>>7
    {
        const int el = tid & 127, s2 = tid >> 7;
        const float* ef = encf + (size_t)b * (SS * EE) + (size_t)(s2 * 64) * 512 + q * 128 + el;
        const float* wp = sw + s2 * 64;
        float cv = 0.f;
#pragma unroll 8
        for (int s = 0; s < 64; ++s) cv += wp[s] * ef[(size_t)s * 512];
        cpart[s2][el] = cv;
    }
    __syncthreads();
    if (tid < 128) {
        const int e = q * 128 + tid;
        const __bf16 c0 = (__bf16)((cpart[0][tid] + cpart[1][tid]) * inv);
        xh_cur[(size_t)b * 1024 + e] = c0;
        XHN[(size_t)(t * 64 + b) * 1024 + 512 + e] = c0;
    } else {
        const int e = q * 128 + (tid - 128);
        const int tok = (t == 0) ? 0 : tgt[b * TT + t - 1];
        xh_cur[(size_t)b * 1024 + 512 + e] = (__bf16)emb[(size_t)tok * 512 + e];
    }
}

// ---------------------------------------------------------------------------
// Gates GEMM (bf16 MFMA) + fused LSTM pointwise (round-4 proven). 64 x 256thr.
// ---------------------------------------------------------------------------
template<bool BF16W>
__global__ __launch_bounds__(256) void gemm_gates_lstm(
    const __bf16* __restrict__ h_old, const __bf16* __restrict__ xh_ce,
    const float* __restrict__ W_ih, const float* __restrict__ W_hh,
    const __bf16* __restrict__ Wg,
    const float* __restrict__ b_ih, const float* __restrict__ b_hh,
    float* __restrict__ hbuf, float* __restrict__ cbuf,
    __bf16* __restrict__ h_new, __bf16* __restrict__ XHN, int t)
{
    __shared__ __align__(16) char smem[18432];
    __bf16 (*Ws)[32][72] = (__bf16 (*)[32][72])smem;
    float  (*Cf)[36]     = (float (*)[36])(smem + 9216);
    const int tid = threadIdx.x;
    const int wv = tid >> 6, lane = tid & 63;
    const int quad = lane >> 4, l16 = lane & 15;
    const int n0 = blockIdx.x * 32;
    const int rowW = tid >> 3, kq8 = (tid & 7) * 8;

    const __bf16* rB = nullptr;
    const float *rH = nullptr, *rI = nullptr;
    if constexpr (BF16W) {
        rB = Wg + (size_t)(n0 + rowW) * 1536 + kq8;
    } else {
        const int nglob = n0 + rowW;
        const int j = ((nglob & 3) << 9) + (nglob >> 2);
        rH = W_hh + (size_t)j * 512;
        rI = W_ih + (size_t)j * 1024;
    }
    auto wld = [&](int it) -> bf16x8 {
        if constexpr (BF16W) {
            return *(const bf16x8*)(rB + it * 64);
        } else {
            const int k = it * 64 + kq8;
            const float* s = (k < 512) ? (rH + k)
                           : (k < 1024 ? rI + k : rI + (k - 1024));
            const float4* q = (const float4*)s;
            return cvt_v(q[0], q[1]);
        }
    };
    const __bf16* aHp = h_old + (size_t)(wv * 16 + l16) * 512 + quad * 8;
    const __bf16* aXp = xh_ce + (size_t)(wv * 16 + l16) * 1024 + quad * 8;

    f32x4 acc[2] = {{0,0,0,0},{0,0,0,0}};
    bf16x8 wcur = wld(0), wnxt = wld(1);
    bf16x8 aC0 = *(const bf16x8*)aHp, aC1 = *(const bf16x8*)(aHp + 32);
    bf16x8 aN0, aN1;
    for (int it = 0; it < 24; ++it) {
        *(bf16x8*)&Ws[it & 1][rowW][kq8] = wcur;
        __syncthreads();
        wcur = wnxt;
        if (it + 2 < 24) wnxt = wld(it + 2);
        if (it + 1 < 24) {
            const int itn = it + 1;
            const __bf16* ap = (itn < 8) ? (aHp + itn * 64) : (aXp + (itn - 8) * 64);
            aN0 = *(const bf16x8*)ap; aN1 = *(const bf16x8*)(ap + 32);
        }
#pragma unroll
        for (int c = 0; c < 2; ++c) {
            bf16x8 b0 = *(const bf16x8*)&Ws[it & 1][c * 16 + l16][quad * 8];
            bf16x8 b1 = *(const bf16x8*)&Ws[it & 1][c * 16 + l16][quad * 8 + 32];
            acc[c] = __builtin_amdgcn_mfma_f32_16x16x32_bf16(aC0, b0, acc[c], 0, 0, 0);
            acc[c] = __builtin_amdgcn_mfma_f32_16x16x32_bf16(aC1, b1, acc[c], 0, 0, 0);
        }
        aC0 = aN0; aC1 = aN1;
    }
    __syncthreads();
#pragma unroll
    for (int r = 0; r < 4; ++r) {
        Cf[wv * 16 + quad * 4 + r][ 0 + l16] = acc[0][r];
        Cf[wv * 16 + quad * 4 + r][16 + l16] = acc[1][r];
    }
    __syncthreads();
    const int U0 = n0 >> 2;
#pragma unroll
    for (int pass = 0; pass < 2; ++pass) {
        const int it2 = tid + pass * 256;
        const int bb = it2 >> 3, ul = it2 & 7;
        const int u = U0 + ul;
        const float gi = Cf[bb][4 * ul + 0] + b_ih[u]          + b_hh[u];
        const float gf = Cf[bb][4 * ul + 1] + b_ih[512 + u]    + b_hh[512 + u];
        const float gg = Cf[bb][4 * ul + 2] + b_ih[1024 + u]   + b_hh[1024 + u];
        const float go = Cf[bb][4 * ul + 3] + b_ih[1536 + u]   + b_hh[1536 + u];
        const float si = sigmoid_fast(gi);
        const float sf = sigmoid_fast(gf);
        const float so = sigmoid_fast(go);
        const float cn = sf * cbuf[bb * 512 + u] + si * tanh_fast(gg);
        const float hn = so * tanh_fast(cn);
        cbuf[bb * 512 + u] = cn;
        hbuf[bb * 512 + u] = hn;
        const __bf16 hb = (__bf16)hn;
        h_new[(size_t)bb * 512 + u] = hb;
        XHN[(size_t)(t * 64 + bb) * 1024 + u] = hb;
    }
}

// ---------------------------------------------------------------------------
// Batched logits GEMM, XCD-swizzled + pad 76 (verified round 5).
// ---------------------------------------------------------------------------
template<bool BF16W>
__global__ __launch_bounds__(256) void gemm_out_big(
    const __bf16* __restrict__ XHN,
    const float*  __restrict__ Wo_f,
    const __bf16* __restrict__ Wo_b,
    const float*  __restrict__ b_out,
    float* __restrict__ out)
{
    __shared__ __bf16 Bs[2][64][76];
    const int tid = threadIdx.x;
    const int blks = ((blockIdx.x & 7) << 8) | ((int)blockIdx.x >> 3);
    const int mt = blks & 15;
    const int n0 = (blks >> 4) * 64;
    const int wv = tid >> 6, lane = tid & 63;
    const int quad = lane >> 4, l16 = lane & 15;
    const int row = tid >> 2, cq = tid & 3;

    const __bf16* aP0 = XHN + (size_t)(mt * 128 + wv * 16 + l16) * 1024 + quad * 8;
    const __bf16* aP1 = aP0 + (size_t)64 * 1024;

    f32x4 acc[8] = {{0,0,0,0},{0,0,0,0},{0,0,0,0},{0,0,0,0},
                    {0,0,0,0},{0,0,0,0},{0,0,0,0},{0,0,0,0}};
    float4 wA0, wA1, wA2, wA3, wB0, wB1, wB2, wB3;
    bf16x8 pA0, pA1, pB0, pB1;
    const float*  bsf = nullptr;
    const __bf16* bsb = nullptr;
    if constexpr (BF16W) {
        bsb = Wo_b + (size_t)(n0 + row) * 1024 + cq * 16;
        const bf16x8* q0 = (const bf16x8*)bsb;        pA0 = q0[0]; pA1 = q0[1];
        const bf16x8* q1 = (const bf16x8*)(bsb + 64); pB0 = q1[0]; pB1 = q1[1];
    } else {
        bsf = Wo_f + (size_t)(n0 + row) * 1024 + cq * 16;
        LDW(wA, bsf); LDW(wB, bsf + 64);
    }
    bf16x8 a0C0 = *(const bf16x8*)aP0, a0C1 = *(const bf16x8*)(aP0 + 32);
    bf16x8 a1C0 = *(const bf16x8*)aP1, a1C1 = *(const bf16x8*)(aP1 + 32);
    bf16x8 a0N0, a0N1, a1N0, a1N1;

    for (int it = 0; it < 16; ++it) {
        __bf16* dst = &Bs[it & 1][row][cq * 16];
        if constexpr (BF16W) {
            *(bf16x8*)dst       = pA0;
            *(bf16x8*)(dst + 8) = pA1;
        } else {
            *(bf16x8*)dst       = cvt_v(wA0, wA1);
            *(bf16x8*)(dst + 8) = cvt_v(wA2, wA3);
        }
        __syncthreads();
        if constexpr (BF16W) {
            pA0 = pB0; pA1 = pB1;
            if (it + 2 < 16) {
                const bf16x8* q = (const bf16x8*)(bsb + (it + 2) * 64);
                pB0 = q[0]; pB1 = q[1];
            }
        } else {
            wA0 = wB0; wA1 = wB1; wA2 = wB2; wA3 = wB3;
            if (it + 2 < 16) LDW(wB, bsf + (it + 2) * 64);
        }
        if (it + 1 < 16) {
            const __bf16* ap0 = aP0 + (it + 1) * 64;
            const __bf16* ap1 = aP1 + (it + 1) * 64;
            a0N0 = *(const bf16x8*)ap0; a0N1 = *(const bf16x8*)(ap0 + 32);
            a1N0 = *(const bf16x8*)ap1; a1N1 = *(const bf16x8*)(ap1 + 32);
        }
#pragma unroll
        for (int c = 0; c < 4; ++c) {
            bf16x8 b0 = *(const bf16x8*)&Bs[it & 1][c * 16 + l16][quad * 8];
            bf16x8 b1 = *(const bf16x8*)&Bs[it & 1][c * 16 + l16][quad * 8 + 32];
            acc[c]     = __builtin_amdgcn_mfma_f32_16x16x32_bf16(a0C0, b0, acc[c],     0, 0, 0);
            acc[c]     = __builtin_amdgcn_mfma_f32_16x16x32_bf16(a0C1, b1, acc[c],     0, 0, 0);
            acc[4 + c] = __builtin_amdgcn_mfma_f32_16x16x32_bf16(a1C0, b0, acc[4 + c], 0, 0, 0);
            acc[4 + c] = __builtin_amdgcn_mfma_f32_16x16x32_bf16(a1C1, b1, acc[4 + c], 0, 0, 0);
        }
        a0C0 = a0N0; a0C1 = a0N1; a1C0 = a1N0; a1C1 = a1N1;
    }
    const int nb = n0 + l16;
#pragma unroll
    for (int h2 = 0; h2 < 2; ++h2) {
#pragma unroll
        for (int r = 0; r < 4; ++r) {
            const int rglob = mt * 128 + h2 * 64 + wv * 16 + quad * 4 + r;
            const int tstep = rglob >> 6, bb = rglob & 63;
            float* orow = out + (size_t)bb * (TT * VV) + (size_t)tstep * VV + nb;
            orow[ 0] = acc[h2 * 4 + 0][r] + b_out[nb +  0];
            orow[16] = acc[h2 * 4 + 1][r] + b_out[nb + 16];
            orow[32] = acc[h2 * 4 + 2][r] + b_out[nb + 32];
            orow[48] = acc[h2 * 4 + 3][r] + b_out[nb + 48];
        }
    }
}

// ---------------------------------------------------------------------------
__global__ void k_zero_f(float* p, int n) {
    int i = blockIdx.x * 256 + threadIdx.x;
    if (i < n) p[i] = 0.f;
}
__global__ void k_zero_bf(__bf16* p, int n) {
    int i = blockIdx.x * 256 + threadIdx.x;
    if (i < n) p[i] = (__bf16)0.f;
}

// ---------------------------------------------------------------------------
extern "C" void kernel_launch(void* const* d_in, const int* in_sizes, int n_in,
                              void* d_out, int out_size, void* d_ws, size_t ws_size,
                              hipStream_t stream)
{
    (void)in_sizes; (void)n_in; (void)out_size;
    const float* encf  = (const float*)d_in[0];
    const int*   tgt   = (const int*)  d_in[1];
    const float* emb   = (const float*)d_in[2];
    const float* W_enc = (const float*)d_in[3];
    const float* W_dec = (const float*)d_in[4];
    const float* b_att = (const float*)d_in[5];
    const float* v_att = (const float*)d_in[6];
    const float* W_ih  = (const float*)d_in[7];
    const float* W_hh  = (const float*)d_in[8];
    const float* b_ih  = (const float*)d_in[9];
    const float* b_hh  = (const float*)d_in[10];
    const float* W_out = (const float*)d_in[11];
    const float* b_out = (const float*)d_in[12];
    float* out = (float*)d_out;

    float* ws = (float*)d_ws;
    size_t off = 0;
    auto alloc = [&](size_t n) { float* p = ws + off; off += (n + 255) & ~(size_t)255; return p; };
    float*  encp    = alloc((size_t)BB * SS * AA);
    float*  hbuf    = alloc((size_t)BB * HH);
    float*  cbuf    = alloc((size_t)BB * HH);
    __bf16* xh0     = (__bf16*)alloc((size_t)BB * 1024 / 2);
    __bf16* hb0     = (__bf16*)alloc((size_t)BB * HH / 2);
    __bf16* hb1     = (__bf16*)alloc((size_t)BB * HH / 2);
    __bf16* XHN     = (__bf16*)alloc((size_t)2048 * 1024 / 2);
    __bf16* Wg      = (__bf16*)alloc((size_t)2048 * 1536 / 2);
    const size_t off1 = off;                                   // level-1 watermark (~19.5 MB)
    __bf16* Wo_b    = (__bf16*)alloc((size_t)VV * 1024 / 2);
    const size_t off2 = off;                                   // level-2 watermark (~36 MB)
    __bf16* encf_bf = (__bf16*)alloc((size_t)BB * SS * EE / 2);
    __bf16* WencT   = (__bf16*)alloc((size_t)EE * AA / 2);
    const size_t off3 = off;                                   // level-3 watermark (~45 MB)

    const int level = (off3 * sizeof(float) <= ws_size) ? 3
                    : (off2 * sizeof(float) <= ws_size) ? 2
                    : (off1 * sizeof(float) <= ws_size) ? 1 : 0;

    k_zero_f<<<(2 * BB * HH + 255) / 256, 256, 0, stream>>>(hbuf, 2 * BB * HH);
    k_zero_bf<<<(BB * HH + 255) / 256, 256, 0, stream>>>(hb0, BB * HH);

    // enc_proj
    if (level >= 3) {
        k_cvt_bf16<<<(int)(((size_t)BB * SS * EE / 4 + 255) / 256), 256, 0, stream>>>(
            encf, encf_bf, (size_t)BB * SS * EE / 4);
        k_cvt_wencT<<<AA, 256, 0, stream>>>(W_enc, WencT);
        gemm_encp<<<256, 256, 0, stream>>>(encf_bf, WencT, encp);
    } else {
        gemm_nn<<<dim3(BB * SS / 64, AA / 64), 256, 0, stream>>>(encf, EE, W_enc, AA, encp, AA, EE);
    }

    if (level >= 1) {
        k_cvt_gates<<<2048, 256, 0, stream>>>(W_ih, W_hh, Wg);
        if (level >= 2)
            k_cvt_bf16<<<(int)(((size_t)VV * 1024 / 4 + 255) / 256), 256, 0, stream>>>(
                W_out, Wo_b, (size_t)VV * 1024 / 4);

        for (int t = 0; t < TT; ++t) {
            __bf16* hold = (t & 1) ? hb1 : hb0;
            __bf16* hnew = (t & 1) ? hb0 : hb1;
            attn_step_w<<<256, 256, 0, stream>>>(
                encf, encp, W_dec, b_att, v_att, emb, tgt, hbuf, xh0, XHN, t);
            gemm_gates_lstm<true><<<64, 256, 0, stream>>>(
                hold, xh0, W_ih, W_hh, Wg, b_ih, b_hh, hbuf, cbuf, hnew, XHN, t);
        }
        if (level >= 2)
            gemm_out_big<true><<<2048, 256, 0, stream>>>(XHN, W_out, Wo_b, b_out, out);
        else
            gemm_out_big<false><<<2048, 256, 0, stream>>>(XHN, W_out, Wo_b, b_out, out);
    } else {
        // Minimal-workspace fallback: fp32 weights.
        for (int t = 0; t < TT; ++t) {
            __bf16* hold = (t & 1) ? hb1 : hb0;
            __bf16* hnew = (t & 1) ? hb0 : hb1;
            attn_step_w<<<256, 256, 0, stream>>>(
                encf, encp, W_dec, b_att, v_att, emb, tgt, hbuf, xh0, XHN, t);
            gemm_gates_lstm<false><<<64, 256, 0, stream>>>(
                hold, xh0, W_ih, W_hh, nullptr, b_ih, b_hh, hbuf, cbuf, hnew, XHN, t);
        }
        gemm_out_big<false><<<2048, 256, 0, stream>>>(XHN, W_out, nullptr, b_out, out);
    }
}

// Round 8
// 1155.509 us; speedup vs baseline: 2.1703x; 1.6961x over previous
//
#include <hip/hip_runtime.h>
#include <math.h>

// B=64, S=128, E=512, H=512, A=256, V=8192, T=32
#define BB 64
#define SS 128
#define EE 512
#define HH 512
#define AA 256
#define VV 8192
#define TT 32

typedef __bf16 bf16x8 __attribute__((ext_vector_type(8)));
typedef __bf16 bf16x4 __attribute__((ext_vector_type(4)));
typedef float  f32x4  __attribute__((ext_vector_type(4)));

__device__ __forceinline__ bf16x8 cvt_v(float4 u, float4 v) {
    bf16x8 r;
    r[0] = (__bf16)u.x; r[1] = (__bf16)u.y; r[2] = (__bf16)u.z; r[3] = (__bf16)u.w;
    r[4] = (__bf16)v.x; r[5] = (__bf16)v.y; r[6] = (__bf16)v.z; r[7] = (__bf16)v.w;
    return r;
}

__device__ __forceinline__ float tanh_fast(float x) {
    x = fminf(15.f, fmaxf(-15.f, x));
    float e = __expf(2.f * x);
    return (e - 1.f) / (e + 1.f);
}
__device__ __forceinline__ float sigmoid_fast(float x) {
    return 1.f / (1.f + __expf(-x));
}

#define LDW(d, p) { const float4* q_ = (const float4*)(p); d##0 = q_[0]; d##1 = q_[1]; d##2 = q_[2]; d##3 = q_[3]; }

// ---------------------------------------------------------------------------
// fp32 GEMM (NN): fallback enc_proj (levels < 3).
// ---------------------------------------------------------------------------
__global__ __launch_bounds__(256) void gemm_nn(
    const float* __restrict__ A, int lda,
    const float* __restrict__ B, int ldb,
    float* __restrict__ C, int ldc, int K)
{
    __shared__ float As[16][68];
    __shared__ float Bs[16][68];
    const int tid = threadIdx.x;
    const int m0 = blockIdx.x * 64, n0 = blockIdx.y * 64;
    const int row = tid >> 2, kq = (tid & 3) * 4;
    const int kk = tid >> 4, nq = (tid & 15) * 4;
    const int tm = tid >> 4, tn = tid & 15;
    float acc[4][4] = {};
    for (int k0 = 0; k0 < K; k0 += 16) {
        float4 av = *(const float4*)(A + (size_t)(m0 + row) * lda + k0 + kq);
        float4 bv = *(const float4*)(B + (size_t)(k0 + kk) * ldb + n0 + nq);
        As[kq + 0][row] = av.x; As[kq + 1][row] = av.y;
        As[kq + 2][row] = av.z; As[kq + 3][row] = av.w;
        *(float4*)&Bs[kk][nq] = bv;
        __syncthreads();
#pragma unroll
        for (int k = 0; k < 16; ++k) {
            float4 a = *(const float4*)&As[k][tm * 4];
            float4 b = *(const float4*)&Bs[k][tn * 4];
            acc[0][0] += a.x * b.x; acc[0][1] += a.x * b.y; acc[0][2] += a.x * b.z; acc[0][3] += a.x * b.w;
            acc[1][0] += a.y * b.x; acc[1][1] += a.y * b.y; acc[1][2] += a.y * b.z; acc[1][3] += a.y * b.w;
            acc[2][0] += a.z * b.x; acc[2][1] += a.z * b.y; acc[2][2] += a.z * b.z; acc[2][3] += a.z * b.w;
            acc[3][0] += a.w * b.x; acc[3][1] += a.w * b.y; acc[3][2] += a.w * b.z; acc[3][3] += a.w * b.w;
        }
        __syncthreads();
    }
#pragma unroll
    for (int i = 0; i < 4; ++i) {
        float4 r = make_float4(acc[i][0], acc[i][1], acc[i][2], acc[i][3]);
        *(float4*)(C + (size_t)(m0 + tm * 4 + i) * ldc + n0 + tn * 4) = r;
    }
}

// ---------------------------------------------------------------------------
// One-time conversions.
// ---------------------------------------------------------------------------
__global__ __launch_bounds__(256) void k_cvt_bf16(
    const float* __restrict__ src, __bf16* __restrict__ dst, size_t n4)
{
    size_t i = (size_t)blockIdx.x * 256 + threadIdx.x;
    if (i < n4) {
        float4 v = *(const float4*)(src + i * 4);
        bf16x4 r;
        r[0] = (__bf16)v.x; r[1] = (__bf16)v.y; r[2] = (__bf16)v.z; r[3] = (__bf16)v.w;
        *(bf16x4*)(dst + i * 4) = r;
    }
}

__global__ __launch_bounds__(256) void k_cvt_gates(
    const float* __restrict__ W_ih, const float* __restrict__ W_hh,
    __bf16* __restrict__ Wg)
{
    const int n = blockIdx.x;
    const int j = ((n & 3) << 9) + (n >> 2);
    for (int k = threadIdx.x * 4; k < 1536; k += 1024) {
        const float* src = (k < 512)  ? (W_hh + (size_t)j * 512 + k)
                         : (k < 1024) ? (W_ih + (size_t)j * 1024 + k)
                                      : (W_ih + (size_t)j * 1024 + (k - 1024));
        float4 v = *(const float4*)src;
        bf16x4 r;
        r[0] = (__bf16)v.x; r[1] = (__bf16)v.y; r[2] = (__bf16)v.z; r[3] = (__bf16)v.w;
        *(bf16x4*)(Wg + (size_t)n * 1536 + k) = r;
    }
}

// W_encT[a][k] = W_enc[k][a], bf16.
__global__ __launch_bounds__(256) void k_cvt_wencT(
    const float* __restrict__ W_enc, __bf16* __restrict__ WT)
{
    const int a = blockIdx.x;
    for (int k = threadIdx.x; k < 512; k += 256)
        WT[(size_t)a * 512 + k] = (__bf16)W_enc[(size_t)k * 256 + a];
}

// ---------------------------------------------------------------------------
// MFMA enc_proj: encp[8192][256] = encf_bf[8192][512] @ W_encT[256][512]^T.
// (verified round 7: replaced the 51 us fp32 gemm_nn, absmax unchanged)
// ---------------------------------------------------------------------------
__global__ __launch_bounds__(256) void gemm_encp(
    const __bf16* __restrict__ A,    // [8192][512]
    const __bf16* __restrict__ Bw,   // [256][512]
    float* __restrict__ C)           // [8192][256]
{
    __shared__ __bf16 Bs[2][64][76];
    const int tid = threadIdx.x;
    const int mt = (int)blockIdx.x >> 2;
    const int n0 = ((int)blockIdx.x & 3) * 64;
    const int wv = tid >> 6, lane = tid & 63;
    const int quad = lane >> 4, l16 = lane & 15;
    const int row = tid >> 2, cq = tid & 3;

    const __bf16* aP0 = A + (size_t)(mt * 128 + wv * 16 + l16) * 512 + quad * 8;
    const __bf16* aP1 = aP0 + (size_t)64 * 512;

    f32x4 acc[8] = {{0,0,0,0},{0,0,0,0},{0,0,0,0},{0,0,0,0},
                    {0,0,0,0},{0,0,0,0},{0,0,0,0},{0,0,0,0}};
    const __bf16* bsb = Bw + (size_t)(n0 + row) * 512 + cq * 16;
    bf16x8 pA0 = ((const bf16x8*)bsb)[0], pA1 = ((const bf16x8*)bsb)[1];
    bf16x8 pB0 = ((const bf16x8*)(bsb + 64))[0], pB1 = ((const bf16x8*)(bsb + 64))[1];
    bf16x8 a0C0 = *(const bf16x8*)aP0, a0C1 = *(const bf16x8*)(aP0 + 32);
    bf16x8 a1C0 = *(const bf16x8*)aP1, a1C1 = *(const bf16x8*)(aP1 + 32);
    bf16x8 a0N0, a0N1, a1N0, a1N1;

    for (int it = 0; it < 8; ++it) {
        __bf16* dst = &Bs[it & 1][row][cq * 16];
        *(bf16x8*)dst       = pA0;
        *(bf16x8*)(dst + 8) = pA1;
        __syncthreads();
        pA0 = pB0; pA1 = pB1;
        if (it + 2 < 8) {
            const bf16x8* q = (const bf16x8*)(bsb + (it + 2) * 64);
            pB0 = q[0]; pB1 = q[1];
        }
        if (it + 1 < 8) {
            const __bf16* ap0 = aP0 + (it + 1) * 64;
            const __bf16* ap1 = aP1 + (it + 1) * 64;
            a0N0 = *(const bf16x8*)ap0; a0N1 = *(const bf16x8*)(ap0 + 32);
            a1N0 = *(const bf16x8*)ap1; a1N1 = *(const bf16x8*)(ap1 + 32);
        }
#pragma unroll
        for (int c = 0; c < 4; ++c) {
            bf16x8 b0 = *(const bf16x8*)&Bs[it & 1][c * 16 + l16][quad * 8];
            bf16x8 b1 = *(const bf16x8*)&Bs[it & 1][c * 16 + l16][quad * 8 + 32];
            acc[c]     = __builtin_amdgcn_mfma_f32_16x16x32_bf16(a0C0, b0, acc[c],     0, 0, 0);
            acc[c]     = __builtin_amdgcn_mfma_f32_16x16x32_bf16(a0C1, b1, acc[c],     0, 0, 0);
            acc[4 + c] = __builtin_amdgcn_mfma_f32_16x16x32_bf16(a1C0, b0, acc[4 + c], 0, 0, 0);
            acc[4 + c] = __builtin_amdgcn_mfma_f32_16x16x32_bf16(a1C1, b1, acc[4 + c], 0, 0, 0);
        }
        a0C0 = a0N0; a0C1 = a0N1; a1C0 = a1N0; a1C1 = a1N1;
    }
    const int nb = n0 + l16;
#pragma unroll
    for (int h2 = 0; h2 < 2; ++h2) {
#pragma unroll
        for (int r = 0; r < 4; ++r) {
            const int rglob = mt * 128 + h2 * 64 + wv * 16 + quad * 4 + r;
            float* orow = C + (size_t)rglob * 256 + nb;
            orow[ 0] = acc[h2 * 4 + 0][r];
            orow[16] = acc[h2 * 4 + 1][r];
            orow[32] = acc[h2 * 4 + 2][r];
            orow[48] = acc[h2 * 4 + 3][r];
        }
    }
}

// ---------------------------------------------------------------------------
// Attention step — ROUND-4 PROVEN BODY (64 blocks x 1024 thr, split-K dec-proj).
// Writes xh_cur = [ctx|emb] bf16 AND ctx into XHN[t*64+b][512..1023].
// ---------------------------------------------------------------------------
__global__ __launch_bounds__(1024) void attn_step(
    const float* __restrict__ encf, const float* __restrict__ encp,
    const float* __restrict__ W_dec, const float* __restrict__ b_att,
    const float* __restrict__ v_att, const float* __restrict__ emb,
    const int*   __restrict__ tgt, const float* __restrict__ h,
    __bf16* __restrict__ xh_cur, __bf16* __restrict__ XHN, int t)
{
    const int b = blockIdx.x;
    const int tid = threadIdx.x;
    __shared__ float sh[512];
    __shared__ float sdec[256];
    __shared__ float sv[256];
    __shared__ float sw[128], st[128];
    __shared__ float part[4][256];
    __shared__ float cpart[2][512];

    if (tid < 512) sh[tid] = h[(size_t)b * 512 + tid];
    else if (tid < 768) sv[tid - 512] = v_att[tid - 512];
    __syncthreads();
    {
        const int a = tid & 255, kq = tid >> 8;
        const float* w = W_dec + (size_t)kq * 128 * 256 + a;
        const float* hp = sh + kq * 128;
        float s = 0.f;
#pragma unroll 8
        for (int k = 0; k < 128; ++k) s += hp[k] * w[(size_t)k * 256];
        part[kq][a] = s;
    }
    __syncthreads();
    if (tid < 256)
        sdec[tid] = part[0][tid] + part[1][tid] + part[2][tid] + part[3][tid] + b_att[tid];
    __syncthreads();
    {
        const int wv = tid >> 6, lane = tid & 63;
#pragma unroll
        for (int i = 0; i < 8; ++i) {
            const int s = wv * 8 + i;
            const float* ep = encp + ((size_t)b * 128 + s) * 256;
            float sum = 0.f;
#pragma unroll
            for (int c = 0; c < 4; ++c) {
                int a = lane + 64 * c;
                sum += tanh_fast(ep[a] + sdec[a]) * sv[a];
            }
#pragma unroll
            for (int off = 32; off > 0; off >>= 1) sum += __shfl_down(sum, off);
            if (lane == 0) sw[s] = sum;
        }
    }
    __syncthreads();
    if (tid < 128) st[tid] = sw[tid];
    __syncthreads();
    for (int off = 64; off > 0; off >>= 1) {
        if (tid < off) st[tid] = fmaxf(st[tid], st[tid + off]);
        __syncthreads();
    }
    const float mx = st[0];
    __syncthreads();
    if (tid < 128) { float ex = __expf(sw[tid] - mx); sw[tid] = ex; st[tid] = ex; }
    __syncthreads();
    for (int off = 64; off > 0; off >>= 1) {
        if (tid < off) st[tid] += st[tid + off];
        __syncthreads();
    }
    {
        const int e = tid & 511, half = tid >> 9;
        const float* ef = encf + (size_t)b * (SS * EE) + (size_t)half * 64 * 512 + e;
        const float* wp = sw + half * 64;
        float cv = 0.f;
#pragma unroll 8
        for (int s = 0; s < 64; ++s) cv += wp[s] * ef[(size_t)s * 512];
        cpart[half][e] = cv;
    }
    __syncthreads();
    const float inv = 1.f / st[0];
    if (tid < 512) {
        const __bf16 cv = (__bf16)((cpart[0][tid] + cpart[1][tid]) * inv);
        xh_cur[(size_t)b * 1024 + tid] = cv;
        XHN[(size_t)(t * 64 + b) * 1024 + 512 + tid] = cv;
    } else {
        const int e = tid - 512;
        const int tok = (t == 0) ? 0 : tgt[b * TT + t - 1];
        xh_cur[(size_t)b * 1024 + 512 + e] = (__bf16)emb[(size_t)tok * 512 + e];
    }
}

// ---------------------------------------------------------------------------
// Gates GEMM (bf16 MFMA) + fused LSTM pointwise (round-4 proven). 64 x 256thr.
// ---------------------------------------------------------------------------
template<bool BF16W>
__global__ __launch_bounds__(256) void gemm_gates_lstm(
    const __bf16* __restrict__ h_old, const __bf16* __restrict__ xh_ce,
    const float* __restrict__ W_ih, const float* __restrict__ W_hh,
    const __bf16* __restrict__ Wg,
    const float* __restrict__ b_ih, const float* __restrict__ b_hh,
    float* __restrict__ hbuf, float* __restrict__ cbuf,
    __bf16* __restrict__ h_new, __bf16* __restrict__ XHN, int t)
{
    __shared__ __align__(16) char smem[18432];
    __bf16 (*Ws)[32][72] = (__bf16 (*)[32][72])smem;
    float  (*Cf)[36]     = (float (*)[36])(smem + 9216);
    const int tid = threadIdx.x;
    const int wv = tid >> 6, lane = tid & 63;
    const int quad = lane >> 4, l16 = lane & 15;
    const int n0 = blockIdx.x * 32;
    const int rowW = tid >> 3, kq8 = (tid & 7) * 8;

    const __bf16* rB = nullptr;
    const float *rH = nullptr, *rI = nullptr;
    if constexpr (BF16W) {
        rB = Wg + (size_t)(n0 + rowW) * 1536 + kq8;
    } else {
        const int nglob = n0 + rowW;
        const int j = ((nglob & 3) << 9) + (nglob >> 2);
        rH = W_hh + (size_t)j * 512;
        rI = W_ih + (size_t)j * 1024;
    }
    auto wld = [&](int it) -> bf16x8 {
        if constexpr (BF16W) {
            return *(const bf16x8*)(rB + it * 64);
        } else {
            const int k = it * 64 + kq8;
            const float* s = (k < 512) ? (rH + k)
                           : (k < 1024 ? rI + k : rI + (k - 1024));
            const float4* q = (const float4*)s;
            return cvt_v(q[0], q[1]);
        }
    };
    const __bf16* aHp = h_old + (size_t)(wv * 16 + l16) * 512 + quad * 8;
    const __bf16* aXp = xh_ce + (size_t)(wv * 16 + l16) * 1024 + quad * 8;

    f32x4 acc[2] = {{0,0,0,0},{0,0,0,0}};
    bf16x8 wcur = wld(0), wnxt = wld(1);
    bf16x8 aC0 = *(const bf16x8*)aHp, aC1 = *(const bf16x8*)(aHp + 32);
    bf16x8 aN0, aN1;
    for (int it = 0; it < 24; ++it) {
        *(bf16x8*)&Ws[it & 1][rowW][kq8] = wcur;
        __syncthreads();
        wcur = wnxt;
        if (it + 2 < 24) wnxt = wld(it + 2);
        if (it + 1 < 24) {
            const int itn = it + 1;
            const __bf16* ap = (itn < 8) ? (aHp + itn * 64) : (aXp + (itn - 8) * 64);
            aN0 = *(const bf16x8*)ap; aN1 = *(const bf16x8*)(ap + 32);
        }
#pragma unroll
        for (int c = 0; c < 2; ++c) {
            bf16x8 b0 = *(const bf16x8*)&Ws[it & 1][c * 16 + l16][quad * 8];
            bf16x8 b1 = *(const bf16x8*)&Ws[it & 1][c * 16 + l16][quad * 8 + 32];
            acc[c] = __builtin_amdgcn_mfma_f32_16x16x32_bf16(aC0, b0, acc[c], 0, 0, 0);
            acc[c] = __builtin_amdgcn_mfma_f32_16x16x32_bf16(aC1, b1, acc[c], 0, 0, 0);
        }
        aC0 = aN0; aC1 = aN1;
    }
    __syncthreads();
#pragma unroll
    for (int r = 0; r < 4; ++r) {
        Cf[wv * 16 + quad * 4 + r][ 0 + l16] = acc[0][r];
        Cf[wv * 16 + quad * 4 + r][16 + l16] = acc[1][r];
    }
    __syncthreads();
    const int U0 = n0 >> 2;
#pragma unroll
    for (int pass = 0; pass < 2; ++pass) {
        const int it2 = tid + pass * 256;
        const int bb = it2 >> 3, ul = it2 & 7;
        const int u = U0 + ul;
        const float gi = Cf[bb][4 * ul + 0] + b_ih[u]          + b_hh[u];
        const float gf = Cf[bb][4 * ul + 1] + b_ih[512 + u]    + b_hh[512 + u];
        const float gg = Cf[bb][4 * ul + 2] + b_ih[1024 + u]   + b_hh[1024 + u];
        const float go = Cf[bb][4 * ul + 3] + b_ih[1536 + u]   + b_hh[1536 + u];
        const float si = sigmoid_fast(gi);
        const float sf = sigmoid_fast(gf);
        const float so = sigmoid_fast(go);
        const float cn = sf * cbuf[bb * 512 + u] + si * tanh_fast(gg);
        const float hn = so * tanh_fast(cn);
        cbuf[bb * 512 + u] = cn;
        hbuf[bb * 512 + u] = hn;
        const __bf16 hb = (__bf16)hn;
        h_new[(size_t)bb * 512 + u] = hb;
        XHN[(size_t)(t * 64 + bb) * 1024 + u] = hb;
    }
}

// ---------------------------------------------------------------------------
// Batched logits GEMM, XCD-swizzled + pad 76 + NONTEMPORAL out stores
// (out writes 64 MB fp32; bypassing L2 keeps the Wo slice resident).
// ---------------------------------------------------------------------------
template<bool BF16W>
__global__ __launch_bounds__(256) void gemm_out_big(
    const __bf16* __restrict__ XHN,
    const float*  __restrict__ Wo_f,
    const __bf16* __restrict__ Wo_b,
    const float*  __restrict__ b_out,
    float* __restrict__ out)
{
    __shared__ __bf16 Bs[2][64][76];
    const int tid = threadIdx.x;
    const int blks = ((blockIdx.x & 7) << 8) | ((int)blockIdx.x >> 3);
    const int mt = blks & 15;
    const int n0 = (blks >> 4) * 64;
    const int wv = tid >> 6, lane = tid & 63;
    const int quad = lane >> 4, l16 = lane & 15;
    const int row = tid >> 2, cq = tid & 3;

    const __bf16* aP0 = XHN + (size_t)(mt * 128 + wv * 16 + l16) * 1024 + quad * 8;
    const __bf16* aP1 = aP0 + (size_t)64 * 1024;

    f32x4 acc[8] = {{0,0,0,0},{0,0,0,0},{0,0,0,0},{0,0,0,0},
                    {0,0,0,0},{0,0,0,0},{0,0,0,0},{0,0,0,0}};
    float4 wA0, wA1, wA2, wA3, wB0, wB1, wB2, wB3;
    bf16x8 pA0, pA1, pB0, pB1;
    const float*  bsf = nullptr;
    const __bf16* bsb = nullptr;
    if constexpr (BF16W) {
        bsb = Wo_b + (size_t)(n0 + row) * 1024 + cq * 16;
        const bf16x8* q0 = (const bf16x8*)bsb;        pA0 = q0[0]; pA1 = q0[1];
        const bf16x8* q1 = (const bf16x8*)(bsb + 64); pB0 = q1[0]; pB1 = q1[1];
    } else {
        bsf = Wo_f + (size_t)(n0 + row) * 1024 + cq * 16;
        LDW(wA, bsf); LDW(wB, bsf + 64);
    }
    bf16x8 a0C0 = *(const bf16x8*)aP0, a0C1 = *(const bf16x8*)(aP0 + 32);
    bf16x8 a1C0 = *(const bf16x8*)aP1, a1C1 = *(const bf16x8*)(aP1 + 32);
    bf16x8 a0N0, a0N1, a1N0, a1N1;

    for (int it = 0; it < 16; ++it) {
        __bf16* dst = &Bs[it & 1][row][cq * 16];
        if constexpr (BF16W) {
            *(bf16x8*)dst       = pA0;
            *(bf16x8*)(dst + 8) = pA1;
        } else {
            *(bf16x8*)dst       = cvt_v(wA0, wA1);
            *(bf16x8*)(dst + 8) = cvt_v(wA2, wA3);
        }
        __syncthreads();
        if constexpr (BF16W) {
            pA0 = pB0; pA1 = pB1;
            if (it + 2 < 16) {
                const bf16x8* q = (const bf16x8*)(bsb + (it + 2) * 64);
                pB0 = q[0]; pB1 = q[1];
            }
        } else {
            wA0 = wB0; wA1 = wB1; wA2 = wB2; wA3 = wB3;
            if (it + 2 < 16) LDW(wB, bsf + (it + 2) * 64);
        }
        if (it + 1 < 16) {
            const __bf16* ap0 = aP0 + (it + 1) * 64;
            const __bf16* ap1 = aP1 + (it + 1) * 64;
            a0N0 = *(const bf16x8*)ap0; a0N1 = *(const bf16x8*)(ap0 + 32);
            a1N0 = *(const bf16x8*)ap1; a1N1 = *(const bf16x8*)(ap1 + 32);
        }
#pragma unroll
        for (int c = 0; c < 4; ++c) {
            bf16x8 b0 = *(const bf16x8*)&Bs[it & 1][c * 16 + l16][quad * 8];
            bf16x8 b1 = *(const bf16x8*)&Bs[it & 1][c * 16 + l16][quad * 8 + 32];
            acc[c]     = __builtin_amdgcn_mfma_f32_16x16x32_bf16(a0C0, b0, acc[c],     0, 0, 0);
            acc[c]     = __builtin_amdgcn_mfma_f32_16x16x32_bf16(a0C1, b1, acc[c],     0, 0, 0);
            acc[4 + c] = __builtin_amdgcn_mfma_f32_16x16x32_bf16(a1C0, b0, acc[4 + c], 0, 0, 0);
            acc[4 + c] = __builtin_amdgcn_mfma_f32_16x16x32_bf16(a1C1, b1, acc[4 + c], 0, 0, 0);
        }
        a0C0 = a0N0; a0C1 = a0N1; a1C0 = a1N0; a1C1 = a1N1;
    }
    const int nb = n0 + l16;
#pragma unroll
    for (int h2 = 0; h2 < 2; ++h2) {
#pragma unroll
        for (int r = 0; r < 4; ++r) {
            const int rglob = mt * 128 + h2 * 64 + wv * 16 + quad * 4 + r;
            const int tstep = rglob >> 6, bb = rglob & 63;
            float* orow = out + (size_t)bb * (TT * VV) + (size_t)tstep * VV + nb;
            __builtin_nontemporal_store(acc[h2 * 4 + 0][r] + b_out[nb +  0], orow +  0);
            __builtin_nontemporal_store(acc[h2 * 4 + 1][r] + b_out[nb + 16], orow + 16);
            __builtin_nontemporal_store(acc[h2 * 4 + 2][r] + b_out[nb + 32], orow + 32);
            __builtin_nontemporal_store(acc[h2 * 4 + 3][r] + b_out[nb + 48], orow + 48);
        }
    }
}

// ---------------------------------------------------------------------------
__global__ void k_zero_f(float* p, int n) {
    int i = blockIdx.x * 256 + threadIdx.x;
    if (i < n) p[i] = 0.f;
}
__global__ void k_zero_bf(__bf16* p, int n) {
    int i = blockIdx.x * 256 + threadIdx.x;
    if (i < n) p[i] = (__bf16)0.f;
}

// ---------------------------------------------------------------------------
extern "C" void kernel_launch(void* const* d_in, const int* in_sizes, int n_in,
                              void* d_out, int out_size, void* d_ws, size_t ws_size,
                              hipStream_t stream)
{
    (void)in_sizes; (void)n_in; (void)out_size;
    const float* encf  = (const float*)d_in[0];
    const int*   tgt   = (const int*)  d_in[1];
    const float* emb   = (const float*)d_in[2];
    const float* W_enc = (const float*)d_in[3];
    const float* W_dec = (const float*)d_in[4];
    const float* b_att = (const float*)d_in[5];
    const float* v_att = (const float*)d_in[6];
    const float* W_ih  = (const float*)d_in[7];
    const float* W_hh  = (const float*)d_in[8];
    const float* b_ih  = (const float*)d_in[9];
    const float* b_hh  = (const float*)d_in[10];
    const float* W_out = (const float*)d_in[11];
    const float* b_out = (const float*)d_in[12];
    float* out = (float*)d_out;

    float* ws = (float*)d_ws;
    size_t off = 0;
    auto alloc = [&](size_t n) { float* p = ws + off; off += (n + 255) & ~(size_t)255; return p; };
    float*  encp    = alloc((size_t)BB * SS * AA);
    float*  hbuf    = alloc((size_t)BB * HH);
    float*  cbuf    = alloc((size_t)BB * HH);
    __bf16* xh0     = (__bf16*)alloc((size_t)BB * 1024 / 2);
    __bf16* hb0     = (__bf16*)alloc((size_t)BB * HH / 2);
    __bf16* hb1     = (__bf16*)alloc((size_t)BB * HH / 2);
    __bf16* XHN     = (__bf16*)alloc((size_t)2048 * 1024 / 2);
    __bf16* Wg      = (__bf16*)alloc((size_t)2048 * 1536 / 2);
    const size_t off1 = off;                                   // level-1 watermark (~19.5 MB)
    __bf16* Wo_b    = (__bf16*)alloc((size_t)VV * 1024 / 2);
    const size_t off2 = off;                                   // level-2 watermark (~36 MB)
    __bf16* encf_bf = (__bf16*)alloc((size_t)BB * SS * EE / 2);
    __bf16* WencT   = (__bf16*)alloc((size_t)EE * AA / 2);
    const size_t off3 = off;                                   // level-3 watermark (~45 MB)

    const int level = (off3 * sizeof(float) <= ws_size) ? 3
                    : (off2 * sizeof(float) <= ws_size) ? 2
                    : (off1 * sizeof(float) <= ws_size) ? 1 : 0;

    k_zero_f<<<(2 * BB * HH + 255) / 256, 256, 0, stream>>>(hbuf, 2 * BB * HH);
    k_zero_bf<<<(BB * HH + 255) / 256, 256, 0, stream>>>(hb0, BB * HH);

    // enc_proj
    if (level >= 3) {
        k_cvt_bf16<<<(int)(((size_t)BB * SS * EE / 4 + 255) / 256), 256, 0, stream>>>(
            encf, encf_bf, (size_t)BB * SS * EE / 4);
        k_cvt_wencT<<<AA, 256, 0, stream>>>(W_enc, WencT);
        gemm_encp<<<256, 256, 0, stream>>>(encf_bf, WencT, encp);
    } else {
        gemm_nn<<<dim3(BB * SS / 64, AA / 64), 256, 0, stream>>>(encf, EE, W_enc, AA, encp, AA, EE);
    }

    if (level >= 1) {
        k_cvt_gates<<<2048, 256, 0, stream>>>(W_ih, W_hh, Wg);
        if (level >= 2)
            k_cvt_bf16<<<(int)(((size_t)VV * 1024 / 4 + 255) / 256), 256, 0, stream>>>(
                W_out, Wo_b, (size_t)VV * 1024 / 4);

        for (int t = 0; t < TT; ++t) {
            __bf16* hold = (t & 1) ? hb1 : hb0;
            __bf16* hnew = (t & 1) ? hb0 : hb1;
            attn_step<<<64, 1024, 0, stream>>>(
                encf, encp, W_dec, b_att, v_att, emb, tgt, hbuf, xh0, XHN, t);
            gemm_gates_lstm<true><<<64, 256, 0, stream>>>(
                hold, xh0, W_ih, W_hh, Wg, b_ih, b_hh, hbuf, cbuf, hnew, XHN, t);
        }
        if (level >= 2)
            gemm_out_big<true><<<2048, 256, 0, stream>>>(XHN, W_out, Wo_b, b_out, out);
        else
            gemm_out_big<false><<<2048, 256, 0, stream>>>(XHN, W_out, Wo_b, b_out, out);
    } else {
        // Minimal-workspace fallback: fp32 weights.
        for (int t = 0; t < TT; ++t) {
            __bf16* hold = (t & 1) ? hb1 : hb0;
            __bf16* hnew = (t & 1) ? hb0 : hb1;
            attn_step<<<64, 1024, 0, stream>>>(
                encf, encp, W_dec, b_att, v_att, emb, tgt, hbuf, xh0, XHN, t);
            gemm_gates_lstm<false><<<64, 256, 0, stream>>>(
                hold, xh0, W_ih, W_hh, nullptr, b_ih, b_hh, hbuf, cbuf, hnew, XHN, t);
        }
        gemm_out_big<false><<<2048, 256, 0, stream>>>(XHN, W_out, nullptr, b_out, out);
    }
}